// Round 9
// baseline (169.278 us; speedup 1.0000x reference)
//
#include <hip/hip_runtime.h>

#define N_NODES 20000
#define N_EDGES 640000
#define D 128
#define CAP 128       // per-node bucket capacity (P(deg>128) ~ 0 for Poisson(32))
#define NBINS 157     // 128 nodes per bin
#define PA_BLOCKS 256
#define EPB 2500      // edges per pass-A block (256*2500 = 640000)
#define SLABCAP 40    // per-(block,bin) record cap: Binom(2500,1/157) mean 16, +6 sigma
#define SRC_SPLIT 10000  // low/high src halves (kept from r6 best-known)

typedef __attribute__((ext_vector_type(8))) short bf16x8;
typedef __attribute__((ext_vector_type(4))) float f32x4;

__device__ __forceinline__ short f2bf(float f) {
    union { float f; unsigned u; } un; un.f = f;
    unsigned r = un.u + 0x7fff + ((un.u >> 16) & 1);
    return (short)(r >> 16);
}
__device__ __forceinline__ float bflo(unsigned u) { return __uint_as_float(u << 16); }
__device__ __forceinline__ float bfhi(unsigned u) { return __uint_as_float(u & 0xffff0000u); }

// Non-temporal 8B gather load: nt flag -> no L1 allocation. Targets the
// TCP miss-handling path (the suspected per-line wall); numerics identical.
__device__ __forceinline__ uint2 ntload_u2(const void* p) {
    unsigned long long v =
        __builtin_nontemporal_load((const unsigned long long*)p);
    uint2 r;
    r.x = (unsigned)v;
    r.y = (unsigned)(v >> 32);
    return r;
}

// ---------------------------------------------------------------------------
// Fused prep (identical to r6): slab-scatter edges + x->bf16 + W pack.
// ---------------------------------------------------------------------------
__global__ __launch_bounds__(256) void prep_kernel(
    const float* __restrict__ x,
    const int* __restrict__ src, const int* __restrict__ dst,
    const float* __restrict__ W1_rel, const float* __restrict__ W1_root,
    const float* __restrict__ W2_rel, const float* __restrict__ W2_root,
    unsigned* __restrict__ binned, int* __restrict__ cnts,
    short* __restrict__ xb, short* __restrict__ wpk1, short* __restrict__ wpk2)
{
    const int b = blockIdx.x;
    const int tid = threadIdx.x;
    if (b < PA_BLOCKS) {
        __shared__ int sOff[NBINS];
        for (int i = tid; i < NBINS; i += 256) sOff[i] = 0;
        __syncthreads();
        const int e0 = b * EPB;
        for (int idx = tid; idx < EPB; idx += 256) {
            int d = dst[e0 + idx];
            int s = src[e0 + idx];
            int bin = d >> 7;
            int off = atomicAdd(&sOff[bin], 1);          // LDS atomic
            if (off < SLABCAP)
                binned[(size_t)(bin * PA_BLOCKS + b) * SLABCAP + off] =
                    ((unsigned)(d & 127) << 16) | (unsigned)s;
        }
        __syncthreads();
        for (int i = tid; i < NBINS; i += 256) {
            int c = sOff[i];
            cnts[i * PA_BLOCKS + b] = (c > SLABCAP) ? SLABCAP : c;
        }
    } else if (b < PA_BLOCKS + 2500) {
        int i = (b - PA_BLOCKS) * 256 + tid;
        float4 v = ((const float4*)x)[i];
        ushort4 o;
        o.x = (unsigned short)f2bf(v.x);
        o.y = (unsigned short)f2bf(v.y);
        o.z = (unsigned short)f2bf(v.z);
        o.w = (unsigned short)f2bf(v.w);
        ((ushort4*)xb)[i] = o;
    } else {
        int pb  = b - (PA_BLOCKS + 2500);
        int job = pb >> 4;                   // 0 -> layer1, 1 -> layer2
        int idx = (pb & 15) * 256 + tid;     // 0..4095
        const float* Wrel  = job ? W2_rel  : W1_rel;
        const float* Wroot = job ? W2_root : W1_root;
        short* Wpk = job ? wpk2 : wpk1;
        int lane = idx & 63;
        int ct   = (idx >> 6) & 7;
        int t    = idx >> 9;
        const float* W = (t < 4) ? Wrel : Wroot;
        int k0  = (t & 3) * 32 + (lane >> 4) * 8;
        int col = ct * 16 + (lane & 15);
        bf16x8 pk;
#pragma unroll
        for (int j = 0; j < 8; j++)
            pk[j] = f2bf(W[(size_t)(k0 + j) * D + col]);
        ((bf16x8*)Wpk)[idx] = pk;
    }
}

// ---------------------------------------------------------------------------
// Pass B (identical to r6): split placement (lo from front, hi from back),
// packed cnt = nlo | nhi<<16. Zero device-scope atomics.
// ---------------------------------------------------------------------------
__global__ __launch_bounds__(256) void binplace_kernel(
    const unsigned* __restrict__ binned, const int* __restrict__ cnts,
    unsigned short* __restrict__ buckets, int* __restrict__ cnt)
{
    __shared__ int lo[128];
    __shared__ int hi[128];
    const int bin = blockIdx.x;
    const int tid = threadIdx.x;
    if (tid < 128) { lo[tid] = 0; hi[tid] = 0; }
    __syncthreads();
    int c = cnts[bin * PA_BLOCKS + tid];
    const unsigned* rec = binned + (size_t)(bin * PA_BLOCKS + tid) * SLABCAP;
    for (int i = 0; i < c; i++) {
        unsigned u = rec[i];
        int nl = (int)(u >> 16);
        unsigned s = u & 0xffffu;
        if ((int)s < SRC_SPLIT) {
            int slot = atomicAdd(&lo[nl], 1);            // LDS atomic
            if (slot < CAP)
                buckets[(((bin << 7) | nl) << 7) + slot] = (unsigned short)s;
        } else {
            int slot = CAP - 1 - atomicAdd(&hi[nl], 1);  // fill from the back
            if (slot >= 0)
                buckets[(((bin << 7) | nl) << 7) + slot] = (unsigned short)s;
        }
    }
    __syncthreads();
    int node = (bin << 7) + tid;
    if (tid < 128 && node < N_NODES) {
        int nlo = lo[tid]; if (nlo > CAP) nlo = CAP;
        int nhi = hi[tid]; if (nhi > CAP - nlo) nhi = CAP - nlo;
        cnt[node] = nlo | (nhi << 16);
    }
}

// ---------------------------------------------------------------------------
// Gather a contiguous slot range [start, start+count) of the node's bucket.
// r6 structure; loads are NON-TEMPORAL (no L1 allocate).
// ---------------------------------------------------------------------------
__device__ __forceinline__ void gather_range(
    float4& acc, const short* __restrict__ xin,
    uint2 idxpk, int lane, int start, int count)
{
    const int end = start + count;
    int k = start;
    const int full_end = start + (count & ~7);
    for (; k < full_end; k += 8) {
        uint2 u[8];
#pragma unroll
        for (int q = 0; q < 8; q++) {
            int j = k + q;
            unsigned word = __shfl((j & 2) ? idxpk.y : idxpk.x, j >> 2, 32);
            unsigned sidx = (j & 1) ? (word >> 16) : (word & 0xffffu);
            u[q] = ntload_u2(xin + (size_t)sidx * D + lane * 4);
        }
#pragma unroll
        for (int q = 0; q < 8; q++) {
            acc.x += bflo(u[q].x); acc.y += bfhi(u[q].x);
            acc.z += bflo(u[q].y); acc.w += bfhi(u[q].y);
        }
    }
    if (k < end) {
        uint2 u[8];
#pragma unroll
        for (int q = 0; q < 8; q++) {
            int j  = k + q;
            int jc = (j < end) ? j : (end - 1);
            unsigned word = __shfl((jc & 2) ? idxpk.y : idxpk.x, jc >> 2, 32);
            unsigned sidx = (jc & 1) ? (word >> 16) : (word & 0xffffu);
            u[q] = ntload_u2(xin + (size_t)sidx * D + lane * 4);
        }
#pragma unroll
        for (int q = 0; q < 8; q++) {
            float m = (k + q < end) ? 1.f : 0.f;
            acc.x += m * bflo(u[q].x); acc.y += m * bfhi(u[q].x);
            acc.z += m * bflo(u[q].y); acc.w += m * bfhi(u[q].y);
        }
    }
}

// ---------------------------------------------------------------------------
// Fused layer (identical to r6): 2-pass src-blocked gather + MFMA.
// ---------------------------------------------------------------------------
template <bool RELU, bool OUT_BF16>
__global__ __launch_bounds__(512) void layer_kernel(
    const short* __restrict__ xin,
    const int* __restrict__ cnt,
    const unsigned short* __restrict__ buckets,
    const short* __restrict__ Wpk,
    const float* __restrict__ brel,
    void* __restrict__ outp)
{
    __shared__ short sAgg[16][136];   // stride 272B: 16B-aligned rows

    const int tid  = threadIdx.x;
    const int row0 = blockIdx.x * 16;

    // ---- phase 1: gather-aggregate into LDS (2-pass src blocking) ----
    {
        const int hw   = tid >> 5;       // 0..15 -> node
        const int lane = tid & 31;
        const int node = row0 + hw;
        int nc  = cnt[node];
        int nlo = nc & 0xffff;
        int nhi = nc >> 16;
        uint2 idxpk = *(const uint2*)(buckets + (node << 7) + lane * 4);

        float4 acc = make_float4(0.f, 0.f, 0.f, 0.f);
        gather_range(acc, xin, idxpk, lane, 0, nlo);          // low-src pass
        __syncthreads();                                      // phase-align
        gather_range(acc, xin, idxpk, lane, CAP - nhi, nhi);  // high-src pass

        ushort4 o;
        o.x = (unsigned short)f2bf(acc.x);
        o.y = (unsigned short)f2bf(acc.y);
        o.z = (unsigned short)f2bf(acc.z);
        o.w = (unsigned short)f2bf(acc.w);
        *(ushort4*)&sAgg[hw][lane * 4] = o;
    }
    __syncthreads();

    // ---- phase 2: MFMA, wave = one 16-col tile ----
    const int wave = tid >> 6;          // 0..7
    const int lane = tid & 63;
    const int quad = lane >> 4;
    const int l16  = lane & 15;

    f32x4 acc = (f32x4){0.f, 0.f, 0.f, 0.f};
    const short* arow_x = xin + (size_t)(row0 + l16) * D + quad * 8;
    const bf16x8* wb = (const bf16x8*)Wpk + lane;

#pragma unroll
    for (int t = 0; t < 8; t++) {
        bf16x8 a;
        if (t < 4)
            a = *(const bf16x8*)&sAgg[l16][(t & 3) * 32 + quad * 8];
        else
            a = *(const bf16x8*)(arow_x + (t & 3) * 32);
        bf16x8 bfr = wb[(t * 8 + wave) * 64];
        acc = __builtin_amdgcn_mfma_f32_16x16x32_bf16(a, bfr, acc, 0, 0, 0);
    }

    const int col  = wave * 16 + l16;
    const int orow = row0 + quad * 4;
    const float bias = brel[col];
#pragma unroll
    for (int r = 0; r < 4; r++) {
        float v = acc[r] + bias;
        if (RELU) v = fmaxf(v, 0.f);
        if (OUT_BF16)
            ((short*)outp)[(size_t)(orow + r) * D + col] = f2bf(v);
        else
            ((float*)outp)[(size_t)(orow + r) * D + col] = v;
    }
}

// ---------------------------------------------------------------------------
extern "C" void kernel_launch(void* const* d_in, const int* in_sizes, int n_in,
                              void* d_out, int out_size, void* d_ws, size_t ws_size,
                              hipStream_t stream) {
    const float* x       = (const float*)d_in[0];
    const int*   ei      = (const int*)  d_in[1];
    const float* W1_rel  = (const float*)d_in[2];
    const float* b1_rel  = (const float*)d_in[3];
    const float* W1_root = (const float*)d_in[4];
    const float* W2_rel  = (const float*)d_in[5];
    const float* b2_rel  = (const float*)d_in[6];
    const float* W2_root = (const float*)d_in[7];
    float* out = (float*)d_out;

    // ws layout (16B-aligned blocks)
    char* p = (char*)d_ws;
    short* xb   = (short*)p;  p += (size_t)N_NODES * D * 2;        // 5.12 MB
    short* hb   = (short*)p;  p += (size_t)N_NODES * D * 2;        // 5.12 MB
    short* wpk1 = (short*)p;  p += 65536;                          // 64 KB
    short* wpk2 = (short*)p;  p += 65536;                          // 64 KB
    int*   cnt  = (int*)p;    p += (size_t)N_NODES * 4;            // 80 KB
    unsigned short* buckets = (unsigned short*)p;
    p += (size_t)NBINS * 128 * CAP * 2;                            // 5.14 MB
    unsigned* binned = (unsigned*)p;
    p += (size_t)NBINS * PA_BLOCKS * SLABCAP * 4;                  // 6.43 MB
    int* cnts = (int*)p;                                           // 160 KB

    const int* src = ei;
    const int* dst = ei + N_EDGES;

    // ---- prep: slab-scatter + convert + pack (no memset needed) ----
    prep_kernel<<<PA_BLOCKS + 2500 + 32, 256, 0, stream>>>(
        x, src, dst, W1_rel, W1_root, W2_rel, W2_root,
        binned, cnts, xb, wpk1, wpk2);

    // ---- pass B: split placement into buckets + packed cnt ----
    binplace_kernel<<<NBINS, 256, 0, stream>>>(binned, cnts, buckets, cnt);

    // ---- layer 1 (x -> hb, bf16, relu) ----
    layer_kernel<true, true><<<1250, 512, 0, stream>>>(
        xb, cnt, buckets, wpk1, b1_rel, (void*)hb);

    // ---- layer 2 (hb -> out, fp32) ----
    layer_kernel<false, false><<<1250, 512, 0, stream>>>(
        hb, cnt, buckets, wpk2, b2_rel, (void*)out);
}

// Round 10
// 147.404 us; speedup vs baseline: 1.1484x; 1.1484x over previous
//
#include <hip/hip_runtime.h>

#define N_NODES 20000
#define N_EDGES 640000
#define D 128
#define CAP 128       // per-node bucket capacity (P(deg>128) ~ 0 for Poisson(32))
#define NBINS 157     // 128 nodes per bin
#define PA_BLOCKS 256
#define EPB 2500      // edges per pass-A block (256*2500 = 640000)
#define SLABCAP 40    // per-(block,bin) record cap: Binom(2500,1/157) mean 16, +6 sigma
#define SRC_SPLIT 10000  // low/high src halves

typedef __attribute__((ext_vector_type(8))) short bf16x8;
typedef __attribute__((ext_vector_type(4))) float f32x4;

__device__ __forceinline__ short f2bf(float f) {
    union { float f; unsigned u; } un; un.f = f;
    unsigned r = un.u + 0x7fff + ((un.u >> 16) & 1);
    return (short)(r >> 16);
}
__device__ __forceinline__ float bflo(unsigned u) { return __uint_as_float(u << 16); }
__device__ __forceinline__ float bfhi(unsigned u) { return __uint_as_float(u & 0xffff0000u); }

// ---------------------------------------------------------------------------
// Fused prep (no global atomics, no memset): slab-scatter + convert + pack.
// ---------------------------------------------------------------------------
__global__ __launch_bounds__(256) void prep_kernel(
    const float* __restrict__ x,
    const int* __restrict__ src, const int* __restrict__ dst,
    const float* __restrict__ W1_rel, const float* __restrict__ W1_root,
    const float* __restrict__ W2_rel, const float* __restrict__ W2_root,
    unsigned* __restrict__ binned, int* __restrict__ cnts,
    short* __restrict__ xb, short* __restrict__ wpk1, short* __restrict__ wpk2)
{
    const int b = blockIdx.x;
    const int tid = threadIdx.x;
    if (b < PA_BLOCKS) {
        __shared__ int sOff[NBINS];
        for (int i = tid; i < NBINS; i += 256) sOff[i] = 0;
        __syncthreads();
        const int e0 = b * EPB;
        for (int idx = tid; idx < EPB; idx += 256) {
            int d = dst[e0 + idx];
            int s = src[e0 + idx];
            int bin = d >> 7;
            int off = atomicAdd(&sOff[bin], 1);          // LDS atomic
            if (off < SLABCAP)
                binned[(size_t)(bin * PA_BLOCKS + b) * SLABCAP + off] =
                    ((unsigned)(d & 127) << 16) | (unsigned)s;
        }
        __syncthreads();
        for (int i = tid; i < NBINS; i += 256) {
            int c = sOff[i];
            cnts[i * PA_BLOCKS + b] = (c > SLABCAP) ? SLABCAP : c;
        }
    } else if (b < PA_BLOCKS + 2500) {
        int i = (b - PA_BLOCKS) * 256 + tid;
        float4 v = ((const float4*)x)[i];
        ushort4 o;
        o.x = (unsigned short)f2bf(v.x);
        o.y = (unsigned short)f2bf(v.y);
        o.z = (unsigned short)f2bf(v.z);
        o.w = (unsigned short)f2bf(v.w);
        ((ushort4*)xb)[i] = o;
    } else {
        int pb  = b - (PA_BLOCKS + 2500);
        int job = pb >> 4;                   // 0 -> layer1, 1 -> layer2
        int idx = (pb & 15) * 256 + tid;     // 0..4095
        const float* Wrel  = job ? W2_rel  : W1_rel;
        const float* Wroot = job ? W2_root : W1_root;
        short* Wpk = job ? wpk2 : wpk1;
        int lane = idx & 63;
        int ct   = (idx >> 6) & 7;
        int t    = idx >> 9;
        const float* W = (t < 4) ? Wrel : Wroot;
        int k0  = (t & 3) * 32 + (lane >> 4) * 8;
        int col = ct * 16 + (lane & 15);
        bf16x8 pk;
#pragma unroll
        for (int j = 0; j < 8; j++)
            pk[j] = f2bf(W[(size_t)(k0 + j) * D + col]);
        ((bf16x8*)Wpk)[idx] = pk;
    }
}

// ---------------------------------------------------------------------------
// Pass B: split placement (lo from front, hi from back), packed cnt.
// ---------------------------------------------------------------------------
__global__ __launch_bounds__(256) void binplace_kernel(
    const unsigned* __restrict__ binned, const int* __restrict__ cnts,
    unsigned short* __restrict__ buckets, int* __restrict__ cnt)
{
    __shared__ int lo[128];
    __shared__ int hi[128];
    const int bin = blockIdx.x;
    const int tid = threadIdx.x;
    if (tid < 128) { lo[tid] = 0; hi[tid] = 0; }
    __syncthreads();
    int c = cnts[bin * PA_BLOCKS + tid];
    const unsigned* rec = binned + (size_t)(bin * PA_BLOCKS + tid) * SLABCAP;
    for (int i = 0; i < c; i++) {
        unsigned u = rec[i];
        int nl = (int)(u >> 16);
        unsigned s = u & 0xffffu;
        if ((int)s < SRC_SPLIT) {
            int slot = atomicAdd(&lo[nl], 1);            // LDS atomic
            if (slot < CAP)
                buckets[(((bin << 7) | nl) << 7) + slot] = (unsigned short)s;
        } else {
            int slot = CAP - 1 - atomicAdd(&hi[nl], 1);  // fill from the back
            if (slot >= 0)
                buckets[(((bin << 7) | nl) << 7) + slot] = (unsigned short)s;
        }
    }
    __syncthreads();
    int node = (bin << 7) + tid;
    if (tid < 128 && node < N_NODES) {
        int nlo = lo[tid]; if (nlo > CAP) nlo = CAP;
        int nhi = hi[tid]; if (nhi > CAP - nlo) nhi = CAP - nlo;
        cnt[node] = nlo | (nhi << 16);
    }
}

// ---------------------------------------------------------------------------
// Gather a contiguous slot range [start, start+count) of the node's bucket.
// Plain (L1-allocating) loads — nt variant measured +21 us (r9).
// ---------------------------------------------------------------------------
__device__ __forceinline__ void gather_range(
    float4& acc, const short* __restrict__ xin,
    uint2 idxpk, int lane, int start, int count)
{
    const int end = start + count;
    int k = start;
    const int full_end = start + (count & ~7);
    for (; k < full_end; k += 8) {
        uint2 u[8];
#pragma unroll
        for (int q = 0; q < 8; q++) {
            int j = k + q;
            unsigned word = __shfl((j & 2) ? idxpk.y : idxpk.x, j >> 2, 32);
            unsigned sidx = (j & 1) ? (word >> 16) : (word & 0xffffu);
            u[q] = *(const uint2*)(xin + (size_t)sidx * D + lane * 4);
        }
#pragma unroll
        for (int q = 0; q < 8; q++) {
            acc.x += bflo(u[q].x); acc.y += bfhi(u[q].x);
            acc.z += bflo(u[q].y); acc.w += bfhi(u[q].y);
        }
    }
    if (k < end) {
        uint2 u[8];
#pragma unroll
        for (int q = 0; q < 8; q++) {
            int j  = k + q;
            int jc = (j < end) ? j : (end - 1);
            unsigned word = __shfl((jc & 2) ? idxpk.y : idxpk.x, jc >> 2, 32);
            unsigned sidx = (jc & 1) ? (word >> 16) : (word & 0xffffu);
            u[q] = *(const uint2*)(xin + (size_t)sidx * D + lane * 4);
        }
#pragma unroll
        for (int q = 0; q < 8; q++) {
            float m = (k + q < end) ? 1.f : 0.f;
            acc.x += m * bflo(u[q].x); acc.y += m * bfhi(u[q].x);
            acc.z += m * bflo(u[q].y); acc.w += m * bfhi(u[q].y);
        }
    }
}

// ---------------------------------------------------------------------------
// Fused layer: 2-pass src-blocked gather + MFMA (best-known, r6 = 148.2 us).
// ---------------------------------------------------------------------------
template <bool RELU, bool OUT_BF16>
__global__ __launch_bounds__(512) void layer_kernel(
    const short* __restrict__ xin,
    const int* __restrict__ cnt,
    const unsigned short* __restrict__ buckets,
    const short* __restrict__ Wpk,
    const float* __restrict__ brel,
    void* __restrict__ outp)
{
    __shared__ short sAgg[16][136];   // stride 272B: 16B-aligned rows

    const int tid  = threadIdx.x;
    const int row0 = blockIdx.x * 16;

    // ---- phase 1: gather-aggregate into LDS (2-pass src blocking) ----
    {
        const int hw   = tid >> 5;       // 0..15 -> node
        const int lane = tid & 31;
        const int node = row0 + hw;
        int nc  = cnt[node];
        int nlo = nc & 0xffff;
        int nhi = nc >> 16;
        uint2 idxpk = *(const uint2*)(buckets + (node << 7) + lane * 4);

        float4 acc = make_float4(0.f, 0.f, 0.f, 0.f);
        gather_range(acc, xin, idxpk, lane, 0, nlo);          // low-src pass
        __syncthreads();                                      // phase-align
        gather_range(acc, xin, idxpk, lane, CAP - nhi, nhi);  // high-src pass

        ushort4 o;
        o.x = (unsigned short)f2bf(acc.x);
        o.y = (unsigned short)f2bf(acc.y);
        o.z = (unsigned short)f2bf(acc.z);
        o.w = (unsigned short)f2bf(acc.w);
        *(ushort4*)&sAgg[hw][lane * 4] = o;
    }
    __syncthreads();

    // ---- phase 2: MFMA, wave = one 16-col tile ----
    const int wave = tid >> 6;          // 0..7
    const int lane = tid & 63;
    const int quad = lane >> 4;
    const int l16  = lane & 15;

    f32x4 acc = (f32x4){0.f, 0.f, 0.f, 0.f};
    const short* arow_x = xin + (size_t)(row0 + l16) * D + quad * 8;
    const bf16x8* wb = (const bf16x8*)Wpk + lane;

#pragma unroll
    for (int t = 0; t < 8; t++) {
        bf16x8 a;
        if (t < 4)
            a = *(const bf16x8*)&sAgg[l16][(t & 3) * 32 + quad * 8];
        else
            a = *(const bf16x8*)(arow_x + (t & 3) * 32);
        bf16x8 bfr = wb[(t * 8 + wave) * 64];
        acc = __builtin_amdgcn_mfma_f32_16x16x32_bf16(a, bfr, acc, 0, 0, 0);
    }

    const int col  = wave * 16 + l16;
    const int orow = row0 + quad * 4;
    const float bias = brel[col];
#pragma unroll
    for (int r = 0; r < 4; r++) {
        float v = acc[r] + bias;
        if (RELU) v = fmaxf(v, 0.f);
        if (OUT_BF16)
            ((short*)outp)[(size_t)(orow + r) * D + col] = f2bf(v);
        else
            ((float*)outp)[(size_t)(orow + r) * D + col] = v;
    }
}

// ---------------------------------------------------------------------------
extern "C" void kernel_launch(void* const* d_in, const int* in_sizes, int n_in,
                              void* d_out, int out_size, void* d_ws, size_t ws_size,
                              hipStream_t stream) {
    const float* x       = (const float*)d_in[0];
    const int*   ei      = (const int*)  d_in[1];
    const float* W1_rel  = (const float*)d_in[2];
    const float* b1_rel  = (const float*)d_in[3];
    const float* W1_root = (const float*)d_in[4];
    const float* W2_rel  = (const float*)d_in[5];
    const float* b2_rel  = (const float*)d_in[6];
    const float* W2_root = (const float*)d_in[7];
    float* out = (float*)d_out;

    // ws layout (16B-aligned blocks)
    char* p = (char*)d_ws;
    short* xb   = (short*)p;  p += (size_t)N_NODES * D * 2;        // 5.12 MB
    short* hb   = (short*)p;  p += (size_t)N_NODES * D * 2;        // 5.12 MB
    short* wpk1 = (short*)p;  p += 65536;                          // 64 KB
    short* wpk2 = (short*)p;  p += 65536;                          // 64 KB
    int*   cnt  = (int*)p;    p += (size_t)N_NODES * 4;            // 80 KB
    unsigned short* buckets = (unsigned short*)p;
    p += (size_t)NBINS * 128 * CAP * 2;                            // 5.14 MB
    unsigned* binned = (unsigned*)p;
    p += (size_t)NBINS * PA_BLOCKS * SLABCAP * 4;                  // 6.43 MB
    int* cnts = (int*)p;                                           // 160 KB

    const int* src = ei;
    const int* dst = ei + N_EDGES;

    // ---- prep: slab-scatter + convert + pack (no memset needed) ----
    prep_kernel<<<PA_BLOCKS + 2500 + 32, 256, 0, stream>>>(
        x, src, dst, W1_rel, W1_root, W2_rel, W2_root,
        binned, cnts, xb, wpk1, wpk2);

    // ---- pass B: split placement into buckets + packed cnt ----
    binplace_kernel<<<NBINS, 256, 0, stream>>>(binned, cnts, buckets, cnt);

    // ---- layer 1 (x -> hb, bf16, relu) ----
    layer_kernel<true, true><<<1250, 512, 0, stream>>>(
        xb, cnt, buckets, wpk1, b1_rel, (void*)hb);

    // ---- layer 2 (hb -> out, fp32) ----
    layer_kernel<false, false><<<1250, 512, 0, stream>>>(
        hb, cnt, buckets, wpk2, b2_rel, (void*)out);
}